// Round 6
// baseline (358.048 us; speedup 1.0000x reference)
//
#include <hip/hip_runtime.h>
#include <math.h>

typedef __bf16 bf16;
typedef __bf16 bf16x4 __attribute__((ext_vector_type(4)));
typedef __bf16 bf16x8 __attribute__((ext_vector_type(8)));
typedef float f32x4 __attribute__((ext_vector_type(4)));

#define AS1 __attribute__((address_space(1)))
#define AS3 __attribute__((address_space(3)))

__device__ __forceinline__ void gload_lds16(const bf16* g, bf16* l) {
    __builtin_amdgcn_global_load_lds((const AS1 void*)g, (AS3 void*)l, 16, 0, 0);
}

__device__ __forceinline__ float gelu_fast(float v) {
    // 0.5v(1+tanh(0.79788456(v+0.044715v^3))) == v*sigmoid(1.59576912(v+0.044715v^3))
    const float u = 1.5957691216057308f * (v + 0.044715f * v * v * v);
    return v / (1.0f + __expf(-u));
}

// ---------------- all weight transposes + cast in ONE launch
// src fp32 [K][N] -> dst bf16 [N][K] for 4 matrices
__global__ __launch_bounds__(256)
void wprep_all(const float* __restrict__ qkv_w, const float* __restrict__ proj_w,
               const float* __restrict__ fc1_w, const float* __restrict__ fc2_w,
               bf16* __restrict__ qkv_wt, bf16* __restrict__ proj_wt,
               bf16* __restrict__ fc1_wt, bf16* __restrict__ fc2_wt)
{
    int idx = blockIdx.x * 256 + threadIdx.x;
    const float* src; bf16* dst; int K, N;
    if (idx < 196608)            { src = qkv_w;  dst = qkv_wt;  K = 256;  N = 768; }
    else if (idx < 262144)       { idx -= 196608; src = proj_w; dst = proj_wt; K = 256;  N = 256; }
    else if (idx < 524288)       { idx -= 262144; src = fc1_w;  dst = fc1_wt;  K = 256;  N = 1024; }
    else                         { idx -= 524288; src = fc2_w;  dst = fc2_wt;  K = 1024; N = 256; }
    const int k = idx / N, n = idx % N;
    dst[(long)n * K + k] = (bf16)src[idx];
}

// ---------------- LN1 + cyclic shift(-4,-4) + window partition -> xw bf16 [B*64win][64][256]
__global__ __launch_bounds__(256)
void ln1_window(const float* __restrict__ x, const float* __restrict__ g,
                const float* __restrict__ be, bf16* __restrict__ xw)
{
    const int t = threadIdx.x;
    const int lane = t & 63;
    const int w = t >> 6;
    const long tok = (long)blockIdx.x * 4 + w;
    const float4 v = ((const float4*)(x + tok * 256))[lane];
    float sum = v.x + v.y + v.z + v.w;
    float sq  = v.x * v.x + v.y * v.y + v.z * v.z + v.w * v.w;
#pragma unroll
    for (int m = 32; m >= 1; m >>= 1) {
        sum += __shfl_xor(sum, m, 64);
        sq  += __shfl_xor(sq,  m, 64);
    }
    const float mean = sum * (1.0f / 256.0f);
    const float var  = sq * (1.0f / 256.0f) - mean * mean;
    const float rstd = rsqrtf(var + 1e-5f);
    const float4 gv = ((const float4*)g)[lane];
    const float4 bv = ((const float4*)be)[lane];
    bf16x4 ov;
    ov[0] = (bf16)((v.x - mean) * rstd * gv.x + bv.x);
    ov[1] = (bf16)((v.y - mean) * rstd * gv.y + bv.y);
    ov[2] = (bf16)((v.z - mean) * rstd * gv.z + bv.z);
    ov[3] = (bf16)((v.w - mean) * rstd * gv.w + bv.w);
    const int b = (int)(tok >> 12);
    const int l = (int)(tok & 4095);
    const int i = l >> 6, j = l & 63;
    const int ip = (i + 60) & 63, jp = (j + 60) & 63;   // shifted coords
    const int winl = ((ip >> 3) << 3) + (jp >> 3);
    const int n = ((ip & 7) << 3) + (jp & 7);
    const long drow = ((long)b * 64 + winl) * 64 + n;
    *(bf16x4*)(xw + drow * 256 + lane * 4) = ov;
}

// ---------------- LN2: y = x + proj_out, then layernorm -> xn2 bf16
__global__ __launch_bounds__(256)
void ln2_kernel(const float* __restrict__ x, const bf16* __restrict__ pj,
                const float* __restrict__ g, const float* __restrict__ be,
                bf16* __restrict__ xn2)
{
    const int t = threadIdx.x;
    const int lane = t & 63;
    const int w = t >> 6;
    const long tok = (long)blockIdx.x * 4 + w;
    const float4 xv = ((const float4*)(x + tok * 256))[lane];
    const bf16x4 pv = *(const bf16x4*)(pj + tok * 256 + lane * 4);
    float y0 = xv.x + (float)pv[0];
    float y1 = xv.y + (float)pv[1];
    float y2 = xv.z + (float)pv[2];
    float y3 = xv.w + (float)pv[3];
    float sum = y0 + y1 + y2 + y3;
    float sq  = y0 * y0 + y1 * y1 + y2 * y2 + y3 * y3;
#pragma unroll
    for (int m = 32; m >= 1; m >>= 1) {
        sum += __shfl_xor(sum, m, 64);
        sq  += __shfl_xor(sq,  m, 64);
    }
    const float mean = sum * (1.0f / 256.0f);
    const float var  = sq * (1.0f / 256.0f) - mean * mean;
    const float rstd = rsqrtf(var + 1e-5f);
    const float4 gv = ((const float4*)g)[lane];
    const float4 bv = ((const float4*)be)[lane];
    bf16x4 ov;
    ov[0] = (bf16)((y0 - mean) * rstd * gv.x + bv.x);
    ov[1] = (bf16)((y1 - mean) * rstd * gv.y + bv.y);
    ov[2] = (bf16)((y2 - mean) * rstd * gv.z + bv.z);
    ov[3] = (bf16)((y3 - mean) * rstd * gv.w + bv.w);
    *(bf16x4*)(xn2 + tok * 256 + lane * 4) = ov;
}

// ---------------- GEMM 128x128 tile, 4 waves, BK=32, 2-stage double-buffered LDS
// (32 KB -> 5 blocks/CU), single barrier per K-step, XOR-swizzled LDS (0 conflicts),
// XCD-chunked block remap, operand-swapped MFMA -> vectorized 8B/16B stores.
// Per iter: [wait tile t][barrier][stage tile t+1 into other buf][compute tile t]
//   - tile t's loads were issued one full compute-phase earlier (latency hidden)
//   - buffer overwritten only after the barrier proving all waves consumed it
// EPI 0: +bias -> bf16 out[row*N+col]           (QKV)
// EPI 1: +bias -> bf16 out[unwindowed tok*256]  (proj, window-reverse + roll(+4))
// EPI 2: +bias, fast GELU -> bf16 out           (FC1)
// EPI 3: +bias + x residual -> f32 out          (FC2)
template<int EPI>
__global__ __launch_bounds__(256, 5)
void gemm_db(const bf16* __restrict__ A, const bf16* __restrict__ Bt,
             const float* __restrict__ bias, void* __restrict__ outp,
             int N, int K, const float* __restrict__ xres, int gx, int nb)
{
    __shared__ bf16 sA[2][4096];
    __shared__ bf16 sB[2][4096];
    const int t = threadIdx.x;
    const int l = t & 63;
    const int w = t >> 6;
    const int wr = w >> 1, wc = w & 1;
    // XCD-chunked bijective remap: consecutive remapped ids land on one XCD
    const int q = nb >> 3;
    const int id = ((int)blockIdx.x & 7) * q + ((int)blockIdx.x >> 3);
    const long m0 = (long)(id / gx) * 128;
    const long n0 = (long)(id % gx) * 128;

    // staging: 512 16B-chunks per matrix, 2 per thread per matrix (4 loads total)
    long asrc[2], bsrc[2];
    int dst_e[2];
#pragma unroll
    for (int j = 0; j < 2; j++) {
        const int idx = j * 256 + t;          // chunk id 0..511
        const int p = idx >> 3, s = idx & 7;
        const int sl = s ^ (p & 7);           // logical slot
        const int row = 2 * p + (sl >> 2);
        const int ce = (sl & 3) * 8;          // k element offset
        asrc[j] = (m0 + row) * (long)K + ce;
        bsrc[j] = (n0 + row) * (long)K + ce;
        dst_e[j] = idx * 8;                   // linear LDS element offset
    }

    f32x4 acc[4][4];
#pragma unroll
    for (int i = 0; i < 4; i++)
#pragma unroll
        for (int j = 0; j < 4; j++) acc[i][j] = (f32x4){0.f, 0.f, 0.f, 0.f};

    const int KT = K >> 5;
    const int c = l >> 4;                     // k-chunk 0..3
    const int ra = wr * 64 + (l & 15);
    const int rb = wc * 64 + (l & 15);

#define STAGE(bufi, ko)                                                        \
    do {                                                                       \
        _Pragma("unroll")                                                      \
        for (int j = 0; j < 2; j++) {                                          \
            gload_lds16(A + asrc[j] + (ko), &sA[bufi][dst_e[j]]);              \
            gload_lds16(Bt + bsrc[j] + (ko), &sB[bufi][dst_e[j]]);             \
        }                                                                      \
    } while (0)

#define COMPUTE(bufi)                                                          \
    do {                                                                       \
        bf16x8 av[4], bv[4];                                                   \
        _Pragma("unroll")                                                      \
        for (int ni = 0; ni < 4; ni++) {                                       \
            const int row = rb + ni * 16;                                      \
            const int p = row >> 1;                                            \
            const int s = (((row & 1) << 2) + c) ^ (p & 7);                    \
            bv[ni] = *(const bf16x8*)&sB[bufi][(p * 8 + s) * 8];               \
        }                                                                      \
        _Pragma("unroll")                                                      \
        for (int mi = 0; mi < 4; mi++) {                                       \
            const int row = ra + mi * 16;                                      \
            const int p = row >> 1;                                            \
            const int s = (((row & 1) << 2) + c) ^ (p & 7);                    \
            av[mi] = *(const bf16x8*)&sA[bufi][(p * 8 + s) * 8];               \
        }                                                                      \
        _Pragma("unroll")                                                      \
        for (int mi = 0; mi < 4; mi++)                                         \
            _Pragma("unroll")                                                  \
            for (int ni = 0; ni < 4; ni++)                                     \
                acc[mi][ni] = __builtin_amdgcn_mfma_f32_16x16x32_bf16(         \
                    bv[ni], av[mi], acc[mi][ni], 0, 0, 0);                     \
    } while (0)

    // prologue: stage tile 0
    STAGE(0, 0);

    for (int kt = 0; kt < KT; ++kt) {
        const int b = kt & 1;
        // only tile kt's 4 loads are outstanding here (issued one compute ago)
        asm volatile("s_waitcnt vmcnt(0)" ::: "memory");
        __builtin_amdgcn_s_barrier();
        __builtin_amdgcn_sched_barrier(0);
        if (kt + 1 < KT)
            STAGE(b ^ 1, (long)(kt + 1) * 32);   // overwrites buf consumed at kt-1
        COMPUTE(b);
    }
#undef STAGE
#undef COMPUTE

    // epilogue: lane holds out[row][col..col+3] per (mi,ni)
#pragma unroll
    for (int mi = 0; mi < 4; mi++)
#pragma unroll
        for (int ni = 0; ni < 4; ni++) {
            const long row = m0 + wr * 64 + mi * 16 + (l & 15);
            const int col = (int)(n0 + wc * 64 + ni * 16 + (l >> 4) * 4);
            const float4 bz = *(const float4*)&bias[col];
            float v0 = acc[mi][ni][0] + bz.x;
            float v1 = acc[mi][ni][1] + bz.y;
            float v2 = acc[mi][ni][2] + bz.z;
            float v3 = acc[mi][ni][3] + bz.w;
            if constexpr (EPI == 2) {
                v0 = gelu_fast(v0); v1 = gelu_fast(v1);
                v2 = gelu_fast(v2); v3 = gelu_fast(v3);
            }
            if constexpr (EPI == 3) {
                const float4 xr = *(const float4*)&xres[row * N + col];
                float4 ov = {v0 + xr.x, v1 + xr.y, v2 + xr.z, v3 + xr.w};
                *(float4*)&((float*)outp)[row * N + col] = ov;
            } else {
                bf16x4 ov;
                ov[0] = (bf16)v0; ov[1] = (bf16)v1; ov[2] = (bf16)v2; ov[3] = (bf16)v3;
                if constexpr (EPI == 1) {
                    const int gwin = (int)(row >> 6);
                    const int n = (int)(row & 63);
                    const int bb = gwin >> 6, wi = gwin & 63;
                    const int ipp = ((wi >> 3) << 3) + (n >> 3);
                    const int jpp = ((wi & 7) << 3) + (n & 7);
                    const int ii = (ipp + 4) & 63, jj = (jpp + 4) & 63;
                    const long tok = ((long)bb << 12) + (ii << 6) + jj;
                    *(bf16x4*)&((bf16*)outp)[tok * 256 + col] = ov;
                } else {
                    *(bf16x4*)&((bf16*)outp)[row * N + col] = ov;
                }
            }
        }
    (void)xres;
}

// ---------------- per-window attention: 1 block = 1 window, wave w does heads {w, w+4}
__global__ __launch_bounds__(256, 2)
void attn_kernel(const bf16* __restrict__ qkv, const float* __restrict__ rpb,
                 bf16* __restrict__ out)
{
    __shared__ bf16 P_lds[4][64 * 64];
    const int t = threadIdx.x;
    const int lane = t & 63;
    const int w = t >> 6;
    const int win = blockIdx.x;          // 0..1023 = b*64 + wi
    const int wi = win & 63;
    const int lr = lane & 15;
    const int lg = lane >> 4;
    const int lk = lg * 8;
    const long base = (long)win * 64 * 768;
    const float scale = 0.17677669529663687f;   // 32^-0.5
    const int whb = (wi >> 3) << 3;             // shifted-image block bases
    const int wwb = (wi & 7) << 3;
    const f32x4 z4 = {0.f, 0.f, 0.f, 0.f};

    for (int hh = 0; hh < 2; hh++) {
        const int head = w + hh * 4;
        const bf16* qp = qkv + base + head * 32;
        const bf16* kp = qkv + base + 256 + head * 32;
        const bf16* vp = qkv + base + 512 + head * 32;

        bf16x8 aq[4], bk[4];
#pragma unroll
        for (int mi = 0; mi < 4; mi++)
            aq[mi] = *(const bf16x8*)(qp + (mi * 16 + lr) * 768 + lk);
#pragma unroll
        for (int ni = 0; ni < 4; ni++)
            bk[ni] = *(const bf16x8*)(kp + (ni * 16 + lr) * 768 + lk);

        f32x4 s[4][4];
#pragma unroll
        for (int i = 0; i < 4; i++)
#pragma unroll
            for (int j = 0; j < 4; j++) s[i][j] = z4;
#pragma unroll
        for (int mi = 0; mi < 4; mi++)
#pragma unroll
            for (int ni = 0; ni < 4; ni++)
                s[mi][ni] = __builtin_amdgcn_mfma_f32_16x16x32_bf16(aq[mi], bk[ni], s[mi][ni], 0, 0, 0);

        // bias + mask + softmax (row n held by 16 lanes sharing lg, 4 col-tiles each)
#pragma unroll
        for (int mi = 0; mi < 4; mi++)
#pragma unroll
            for (int r = 0; r < 4; r++) {
                const int n = mi * 16 + lg * 4 + r;
                const int gi = whb + (n >> 3);
                const int gj = wwb + (n & 7);
                const int idn = (gi < 56 ? 0 : (gi < 60 ? 1 : 2)) * 3 + (gj < 56 ? 0 : (gj < 60 ? 1 : 2));
                float vals[4];
                float rowmax = -3.0e38f;
#pragma unroll
                for (int ni = 0; ni < 4; ni++) {
                    const int m = ni * 16 + lr;
                    const int gi2 = whb + (m >> 3);
                    const int gj2 = wwb + (m & 7);
                    const int idm = (gi2 < 56 ? 0 : (gi2 < 60 ? 1 : 2)) * 3 + (gj2 < 56 ? 0 : (gj2 < 60 ? 1 : 2));
                    const int dj = (n & 7) - (m & 7);
                    const int di = (n >> 3) - (m >> 3);
                    float sv = s[mi][ni][r] * scale + rpb[((dj + 7) * 15 + (di + 7)) * 8 + head];
                    if (idn == idm) sv -= 100.0f;   // faithful to source: -100 where EQUAL
                    vals[ni] = sv;
                    rowmax = fmaxf(rowmax, sv);
                }
#pragma unroll
                for (int msk = 8; msk >= 1; msk >>= 1)
                    rowmax = fmaxf(rowmax, __shfl_xor(rowmax, msk, 64));
                float rsum = 0.f;
#pragma unroll
                for (int ni = 0; ni < 4; ni++) {
                    const float p = __expf(vals[ni] - rowmax);
                    vals[ni] = p;
                    rsum += p;
                }
#pragma unroll
                for (int msk = 8; msk >= 1; msk >>= 1)
                    rsum += __shfl_xor(rsum, msk, 64);
                const float inv = 1.0f / rsum;
#pragma unroll
                for (int ni = 0; ni < 4; ni++)
                    P_lds[w][n * 64 + ni * 16 + lr] = (bf16)(vals[ni] * inv);
            }

        // PV: O[n][d] = sum_key P[n][key] V[key][d]  (operand-swapped: lane holds
        // 4 consecutive d of one row)
        f32x4 o[4][2];
#pragma unroll
        for (int i = 0; i < 4; i++)
#pragma unroll
            for (int j = 0; j < 2; j++) o[i][j] = z4;
#pragma unroll
        for (int kk = 0; kk < 2; kk++) {
            bf16x8 bv[2];
#pragma unroll
            for (int ni = 0; ni < 2; ni++)
#pragma unroll
                for (int i = 0; i < 8; i++)
                    bv[ni][i] = vp[(kk * 32 + lk + i) * 768 + ni * 16 + lr];
#pragma unroll
            for (int mi = 0; mi < 4; mi++) {
                const bf16x8 ap = *(const bf16x8*)&P_lds[w][(mi * 16 + lr) * 64 + kk * 32 + lk];
#pragma unroll
                for (int ni = 0; ni < 2; ni++)
                    o[mi][ni] = __builtin_amdgcn_mfma_f32_16x16x32_bf16(bv[ni], ap, o[mi][ni], 0, 0, 0);
            }
        }
        // store: lane holds o[mi][ni][0..3] = out[row n=mi*16+lr][d=ni*16+lg*4 ..+3]
#pragma unroll
        for (int mi = 0; mi < 4; mi++)
#pragma unroll
            for (int ni = 0; ni < 2; ni++) {
                const int n = mi * 16 + lr;
                const int d = ni * 16 + lg * 4;
                bf16x4 ov;
                ov[0] = (bf16)o[mi][ni][0]; ov[1] = (bf16)o[mi][ni][1];
                ov[2] = (bf16)o[mi][ni][2]; ov[3] = (bf16)o[mi][ni][3];
                *(bf16x4*)(out + ((long)(win * 64 + n)) * 256 + head * 32 + d) = ov;
            }
    }
}

extern "C" void kernel_launch(void* const* d_in, const int* in_sizes, int n_in,
                              void* d_out, int out_size, void* d_ws, size_t ws_size,
                              hipStream_t stream)
{
    (void)in_sizes; (void)n_in; (void)out_size;
    const float* x      = (const float*)d_in[0];
    const float* n1g    = (const float*)d_in[1];
    const float* n1b    = (const float*)d_in[2];
    const float* qkv_w  = (const float*)d_in[3];
    const float* qkv_b  = (const float*)d_in[4];
    const float* rpb    = (const float*)d_in[5];
    const float* proj_w = (const float*)d_in[6];
    const float* proj_b = (const float*)d_in[7];
    const float* n2g    = (const float*)d_in[8];
    const float* n2b    = (const float*)d_in[9];
    const float* fc1_w  = (const float*)d_in[10];
    const float* fc1_b  = (const float*)d_in[11];
    const float* fc2_w  = (const float*)d_in[12];
    const float* fc2_b  = (const float*)d_in[13];
    float* out = (float*)d_out;

    // workspace plan (total 136,314,880 B = 130 MB):
    //   0        .. 2 MB   : transposed bf16 weights
    //   2 MB     .. 34 MB  : xw  -> later attn_o -> later part of hbuf
    //   34 MB    .. 130 MB : qkvb -> later proj_o (first 32MB) -> part of hbuf
    //   xn2 staged in d_out (first 32 MB as bf16; dead before FC2 writes)
    char* ws = (char*)d_ws;
    bf16* qkv_wt  = (bf16*)(ws + 0);          // 768x256
    bf16* proj_wt = (bf16*)(ws + 393216);     // 256x256
    bf16* fc1_wt  = (bf16*)(ws + 524288);     // 1024x256
    bf16* fc2_wt  = (bf16*)(ws + 1048576);    // 256x1024
    bf16* xw      = (bf16*)(ws + 2097152);    // 32MB  [65536][256]
    bf16* qkvb    = (bf16*)(ws + 35651584);   // 96MB  [65536][768]
    bf16* attn_o  = xw;                       // reuse xw (dead after QKV gemm)
    bf16* proj_o  = qkvb;                     // reuse qkvb (dead after attn), 32MB
    bf16* xn2     = (bf16*)d_out;             // stage LN2 output in d_out
    bf16* hbuf    = xw;                       // 128MB over 2..130MB
    if (ws_size < 136314880ull) return;       // insufficient scratch

    wprep_all<<<3072, 256, 0, stream>>>(qkv_w, proj_w, fc1_w, fc2_w,
                                        qkv_wt, proj_wt, fc1_wt, fc2_wt);

    ln1_window<<<16384, 256, 0, stream>>>(x, n1g, n1b, xw);
    gemm_db<0><<<3072, 256, 0, stream>>>(xw, qkv_wt, qkv_b, qkvb, 768, 256, nullptr, 6, 3072);
    attn_kernel<<<1024, 256, 0, stream>>>(qkvb, rpb, attn_o);
    gemm_db<1><<<1024, 256, 0, stream>>>(attn_o, proj_wt, proj_b, proj_o, 256, 256, nullptr, 2, 1024);
    ln2_kernel<<<16384, 256, 0, stream>>>(x, proj_o, n2g, n2b, xn2);
    gemm_db<2><<<4096, 256, 0, stream>>>(xn2, fc1_wt, fc1_b, hbuf, 1024, 256, nullptr, 8, 4096);
    gemm_db<3><<<1024, 256, 0, stream>>>(hbuf, fc2_wt, fc2_b, out, 256, 1024, x, 2, 1024);
}

// Round 7
// 321.096 us; speedup vs baseline: 1.1151x; 1.1151x over previous
//
#include <hip/hip_runtime.h>
#include <math.h>

typedef __bf16 bf16;
typedef __bf16 bf16x4 __attribute__((ext_vector_type(4)));
typedef __bf16 bf16x8 __attribute__((ext_vector_type(8)));
typedef float f32x4 __attribute__((ext_vector_type(4)));

#define AS1 __attribute__((address_space(1)))
#define AS3 __attribute__((address_space(3)))

__device__ __forceinline__ void gload_lds16(const bf16* g, bf16* l) {
    __builtin_amdgcn_global_load_lds((const AS1 void*)g, (AS3 void*)l, 16, 0, 0);
}

__device__ __forceinline__ float gelu_fast(float v) {
    // 0.5v(1+tanh(0.79788456(v+0.044715v^3))) == v*sigmoid(1.59576912(v+0.044715v^3))
    const float u = 1.5957691216057308f * (v + 0.044715f * v * v * v);
    return v / (1.0f + __expf(-u));
}

// ---------------- all weight transposes + cast in ONE launch
__global__ __launch_bounds__(256)
void wprep_all(const float* __restrict__ qkv_w, const float* __restrict__ proj_w,
               const float* __restrict__ fc1_w, const float* __restrict__ fc2_w,
               bf16* __restrict__ qkv_wt, bf16* __restrict__ proj_wt,
               bf16* __restrict__ fc1_wt, bf16* __restrict__ fc2_wt)
{
    int idx = blockIdx.x * 256 + threadIdx.x;
    const float* src; bf16* dst; int K, N;
    if (idx < 196608)            { src = qkv_w;  dst = qkv_wt;  K = 256;  N = 768; }
    else if (idx < 262144)       { idx -= 196608; src = proj_w; dst = proj_wt; K = 256;  N = 256; }
    else if (idx < 524288)       { idx -= 262144; src = fc1_w;  dst = fc1_wt;  K = 256;  N = 1024; }
    else                         { idx -= 524288; src = fc2_w;  dst = fc2_wt;  K = 1024; N = 256; }
    const int k = idx / N, n = idx % N;
    dst[(long)n * K + k] = (bf16)src[idx];
}

// ---------------- LN1 + cyclic shift(-4,-4) + window partition -> xw bf16 [B*64win][64][256]
__global__ __launch_bounds__(256)
void ln1_window(const float* __restrict__ x, const float* __restrict__ g,
                const float* __restrict__ be, bf16* __restrict__ xw)
{
    const int t = threadIdx.x;
    const int lane = t & 63;
    const int w = t >> 6;
    const long tok = (long)blockIdx.x * 4 + w;
    const float4 v = ((const float4*)(x + tok * 256))[lane];
    float sum = v.x + v.y + v.z + v.w;
    float sq  = v.x * v.x + v.y * v.y + v.z * v.z + v.w * v.w;
#pragma unroll
    for (int m = 32; m >= 1; m >>= 1) {
        sum += __shfl_xor(sum, m, 64);
        sq  += __shfl_xor(sq,  m, 64);
    }
    const float mean = sum * (1.0f / 256.0f);
    const float var  = sq * (1.0f / 256.0f) - mean * mean;
    const float rstd = rsqrtf(var + 1e-5f);
    const float4 gv = ((const float4*)g)[lane];
    const float4 bv = ((const float4*)be)[lane];
    bf16x4 ov;
    ov[0] = (bf16)((v.x - mean) * rstd * gv.x + bv.x);
    ov[1] = (bf16)((v.y - mean) * rstd * gv.y + bv.y);
    ov[2] = (bf16)((v.z - mean) * rstd * gv.z + bv.z);
    ov[3] = (bf16)((v.w - mean) * rstd * gv.w + bv.w);
    const int b = (int)(tok >> 12);
    const int l = (int)(tok & 4095);
    const int i = l >> 6, j = l & 63;
    const int ip = (i + 60) & 63, jp = (j + 60) & 63;   // shifted coords
    const int winl = ((ip >> 3) << 3) + (jp >> 3);
    const int n = ((ip & 7) << 3) + (jp & 7);
    const long drow = ((long)b * 64 + winl) * 64 + n;
    *(bf16x4*)(xw + drow * 256 + lane * 4) = ov;
}

// ---------------- LN2: y = x + proj_out, then layernorm -> xn2 bf16
__global__ __launch_bounds__(256)
void ln2_kernel(const float* __restrict__ x, const bf16* __restrict__ pj,
                const float* __restrict__ g, const float* __restrict__ be,
                bf16* __restrict__ xn2)
{
    const int t = threadIdx.x;
    const int lane = t & 63;
    const int w = t >> 6;
    const long tok = (long)blockIdx.x * 4 + w;
    const float4 xv = ((const float4*)(x + tok * 256))[lane];
    const bf16x4 pv = *(const bf16x4*)(pj + tok * 256 + lane * 4);
    float y0 = xv.x + (float)pv[0];
    float y1 = xv.y + (float)pv[1];
    float y2 = xv.z + (float)pv[2];
    float y3 = xv.w + (float)pv[3];
    float sum = y0 + y1 + y2 + y3;
    float sq  = y0 * y0 + y1 * y1 + y2 * y2 + y3 * y3;
#pragma unroll
    for (int m = 32; m >= 1; m >>= 1) {
        sum += __shfl_xor(sum, m, 64);
        sq  += __shfl_xor(sq,  m, 64);
    }
    const float mean = sum * (1.0f / 256.0f);
    const float var  = sq * (1.0f / 256.0f) - mean * mean;
    const float rstd = rsqrtf(var + 1e-5f);
    const float4 gv = ((const float4*)g)[lane];
    const float4 bv = ((const float4*)be)[lane];
    bf16x4 ov;
    ov[0] = (bf16)((y0 - mean) * rstd * gv.x + bv.x);
    ov[1] = (bf16)((y1 - mean) * rstd * gv.y + bv.y);
    ov[2] = (bf16)((y2 - mean) * rstd * gv.z + bv.z);
    ov[3] = (bf16)((y3 - mean) * rstd * gv.w + bv.w);
    *(bf16x4*)(xn2 + tok * 256 + lane * 4) = ov;
}

// ---------------- GEMM 256x128 tile, 8 waves (512 thr), BK=32, 3-stage counted
// pipeline (R5's best structure), XOR-swizzled LDS (0 conflicts), XCD remap,
// operand-swapped MFMA -> vectorized 8B/16B stores. 72KB dynamic LDS, 2 blocks/CU.
// Per thread per stage: 2 A-loads + 1 B-load -> loop wait = vmcnt(3).
// EPI 0: +bias -> bf16 out[row*N+col]           (QKV)
// EPI 1: +bias -> bf16 out[unwindowed tok*256]  (proj, window-reverse + roll(+4))
// EPI 2: +bias, fast GELU -> bf16 out           (FC1)
// EPI 3: +bias + x residual -> f32 out          (FC2)
template<int EPI>
__global__ __launch_bounds__(512, 2)
void gemm_w(const bf16* __restrict__ A, const bf16* __restrict__ Bt,
            const float* __restrict__ bias, void* __restrict__ outp,
            int N, int K, const float* __restrict__ xres, int gx, int nb)
{
    extern __shared__ bf16 lds[];
    bf16* sA = lds;                 // 3 bufs x 8192 elems (256x32)
    bf16* sB = lds + 3 * 8192;      // 3 bufs x 4096 elems (128x32)
    const int t = threadIdx.x;      // 0..511
    const int l = t & 63;
    const int w = t >> 6;           // 0..7
    const int wr = w >> 1, wc = w & 1;
    // XCD-chunked bijective remap (nb % 8 == 0 for all grids here)
    const int q = nb >> 3;
    const int id = ((int)blockIdx.x & 7) * q + ((int)blockIdx.x >> 3);
    const long m0 = (long)(id / gx) * 256;
    const long n0 = (long)(id % gx) * 128;

    // staging maps: A = 1024 16B-chunks (2/thread), B = 512 (1/thread)
    long asrc[2]; int adst[2];
#pragma unroll
    for (int j = 0; j < 2; j++) {
        const int idx = j * 512 + t;
        const int p = idx >> 3, s = idx & 7;
        const int sl = s ^ (p & 7);
        const int row = 2 * p + (sl >> 2);
        const int ce = (sl & 3) * 8;
        asrc[j] = (m0 + row) * (long)K + ce;
        adst[j] = idx * 8;
    }
    long bsrc; int bdst;
    {
        const int idx = t;
        const int p = idx >> 3, s = idx & 7;
        const int sl = s ^ (p & 7);
        const int row = 2 * p + (sl >> 2);
        const int ce = (sl & 3) * 8;
        bsrc = (n0 + row) * (long)K + ce;
        bdst = idx * 8;
    }

    f32x4 acc[4][4];
#pragma unroll
    for (int i = 0; i < 4; i++)
#pragma unroll
        for (int j = 0; j < 4; j++) acc[i][j] = (f32x4){0.f, 0.f, 0.f, 0.f};

    const int KT = K >> 5;
    const int c = l >> 4;
    const int ra = wr * 64 + (l & 15);   // row in 256
    const int rb = wc * 64 + (l & 15);   // row in 128

#define STAGE(bufi, ko)                                                        \
    do {                                                                       \
        gload_lds16(A + asrc[0] + (ko), &sA[(bufi) * 8192 + adst[0]]);         \
        gload_lds16(A + asrc[1] + (ko), &sA[(bufi) * 8192 + adst[1]]);         \
        gload_lds16(Bt + bsrc + (ko), &sB[(bufi) * 4096 + bdst]);              \
    } while (0)

#define COMPUTE(bufi)                                                          \
    do {                                                                       \
        bf16x8 av[4], bv[4];                                                   \
        _Pragma("unroll")                                                      \
        for (int ni = 0; ni < 4; ni++) {                                       \
            const int row = rb + ni * 16;                                      \
            const int p = row >> 1;                                            \
            const int s = (((row & 1) << 2) + c) ^ (p & 7);                    \
            bv[ni] = *(const bf16x8*)&sB[(bufi) * 4096 + (p * 8 + s) * 8];     \
        }                                                                      \
        _Pragma("unroll")                                                      \
        for (int mi = 0; mi < 4; mi++) {                                       \
            const int row = ra + mi * 16;                                      \
            const int p = row >> 1;                                            \
            const int s = (((row & 1) << 2) + c) ^ (p & 7);                    \
            av[mi] = *(const bf16x8*)&sA[(bufi) * 8192 + (p * 8 + s) * 8];     \
        }                                                                      \
        _Pragma("unroll")                                                      \
        for (int mi = 0; mi < 4; mi++)                                         \
            _Pragma("unroll")                                                  \
            for (int ni = 0; ni < 4; ni++)                                     \
                acc[mi][ni] = __builtin_amdgcn_mfma_f32_16x16x32_bf16(         \
                    bv[ni], av[mi], acc[mi][ni], 0, 0, 0);                     \
    } while (0)

    // prologue: stage tiles 0 and 1 (6 loads outstanding)
    STAGE(0, 0);
    STAGE(1, 32);

    int buf = 0;
    for (int kt = 0; kt < KT - 1; ++kt) {
        // wait tile kt's 3 loads; tile kt+1's 3 stay in flight
        asm volatile("s_waitcnt vmcnt(3)" ::: "memory");
        __builtin_amdgcn_s_barrier();
        __builtin_amdgcn_sched_barrier(0);
        if (kt + 2 < KT) {
            const int nbuf = (buf + 2 >= 3) ? buf - 1 : buf + 2;
            STAGE(nbuf, (long)(kt + 2) * 32);
        }
        COMPUTE(buf);
        buf = (buf + 1 == 3) ? 0 : buf + 1;
    }
    asm volatile("s_waitcnt vmcnt(0)" ::: "memory");
    __builtin_amdgcn_s_barrier();
    __builtin_amdgcn_sched_barrier(0);
    COMPUTE(buf);
#undef STAGE
#undef COMPUTE

    // epilogue: lane holds out[row][col..col+3] per (mi,ni)
#pragma unroll
    for (int mi = 0; mi < 4; mi++)
#pragma unroll
        for (int ni = 0; ni < 4; ni++) {
            const long row = m0 + wr * 64 + mi * 16 + (l & 15);
            const int col = (int)(n0 + wc * 64 + ni * 16 + (l >> 4) * 4);
            const float4 bz = *(const float4*)&bias[col];
            float v0 = acc[mi][ni][0] + bz.x;
            float v1 = acc[mi][ni][1] + bz.y;
            float v2 = acc[mi][ni][2] + bz.z;
            float v3 = acc[mi][ni][3] + bz.w;
            if constexpr (EPI == 2) {
                v0 = gelu_fast(v0); v1 = gelu_fast(v1);
                v2 = gelu_fast(v2); v3 = gelu_fast(v3);
            }
            if constexpr (EPI == 3) {
                const float4 xr = *(const float4*)&xres[row * N + col];
                float4 ov = {v0 + xr.x, v1 + xr.y, v2 + xr.z, v3 + xr.w};
                *(float4*)&((float*)outp)[row * N + col] = ov;
            } else {
                bf16x4 ov;
                ov[0] = (bf16)v0; ov[1] = (bf16)v1; ov[2] = (bf16)v2; ov[3] = (bf16)v3;
                if constexpr (EPI == 1) {
                    const int gwin = (int)(row >> 6);
                    const int n = (int)(row & 63);
                    const int bb = gwin >> 6, wi = gwin & 63;
                    const int ipp = ((wi >> 3) << 3) + (n >> 3);
                    const int jpp = ((wi & 7) << 3) + (n & 7);
                    const int ii = (ipp + 4) & 63, jj = (jpp + 4) & 63;
                    const long tok = ((long)bb << 12) + (ii << 6) + jj;
                    *(bf16x4*)&((bf16*)outp)[tok * 256 + col] = ov;
                } else {
                    *(bf16x4*)&((bf16*)outp)[row * N + col] = ov;
                }
            }
        }
    (void)xres;
}

// ---------------- per-window attention: 1 block = 1 window, wave w does heads {w, w+4}
__global__ __launch_bounds__(256, 2)
void attn_kernel(const bf16* __restrict__ qkv, const float* __restrict__ rpb,
                 bf16* __restrict__ out)
{
    __shared__ bf16 P_lds[4][64 * 64];
    const int t = threadIdx.x;
    const int lane = t & 63;
    const int w = t >> 6;
    const int win = blockIdx.x;          // 0..1023 = b*64 + wi
    const int wi = win & 63;
    const int lr = lane & 15;
    const int lg = lane >> 4;
    const int lk = lg * 8;
    const long base = (long)win * 64 * 768;
    const float scale = 0.17677669529663687f;   // 32^-0.5
    const int whb = (wi >> 3) << 3;             // shifted-image block bases
    const int wwb = (wi & 7) << 3;
    const f32x4 z4 = {0.f, 0.f, 0.f, 0.f};

    for (int hh = 0; hh < 2; hh++) {
        const int head = w + hh * 4;
        const bf16* qp = qkv + base + head * 32;
        const bf16* kp = qkv + base + 256 + head * 32;
        const bf16* vp = qkv + base + 512 + head * 32;

        bf16x8 aq[4], bk[4];
#pragma unroll
        for (int mi = 0; mi < 4; mi++)
            aq[mi] = *(const bf16x8*)(qp + (mi * 16 + lr) * 768 + lk);
#pragma unroll
        for (int ni = 0; ni < 4; ni++)
            bk[ni] = *(const bf16x8*)(kp + (ni * 16 + lr) * 768 + lk);

        f32x4 s[4][4];
#pragma unroll
        for (int i = 0; i < 4; i++)
#pragma unroll
            for (int j = 0; j < 4; j++) s[i][j] = z4;
#pragma unroll
        for (int mi = 0; mi < 4; mi++)
#pragma unroll
            for (int ni = 0; ni < 4; ni++)
                s[mi][ni] = __builtin_amdgcn_mfma_f32_16x16x32_bf16(aq[mi], bk[ni], s[mi][ni], 0, 0, 0);

        // bias + mask + softmax (row n held by 16 lanes sharing lg, 4 col-tiles each)
#pragma unroll
        for (int mi = 0; mi < 4; mi++)
#pragma unroll
            for (int r = 0; r < 4; r++) {
                const int n = mi * 16 + lg * 4 + r;
                const int gi = whb + (n >> 3);
                const int gj = wwb + (n & 7);
                const int idn = (gi < 56 ? 0 : (gi < 60 ? 1 : 2)) * 3 + (gj < 56 ? 0 : (gj < 60 ? 1 : 2));
                float vals[4];
                float rowmax = -3.0e38f;
#pragma unroll
                for (int ni = 0; ni < 4; ni++) {
                    const int m = ni * 16 + lr;
                    const int gi2 = whb + (m >> 3);
                    const int gj2 = wwb + (m & 7);
                    const int idm = (gi2 < 56 ? 0 : (gi2 < 60 ? 1 : 2)) * 3 + (gj2 < 56 ? 0 : (gj2 < 60 ? 1 : 2));
                    const int dj = (n & 7) - (m & 7);
                    const int di = (n >> 3) - (m >> 3);
                    float sv = s[mi][ni][r] * scale + rpb[((dj + 7) * 15 + (di + 7)) * 8 + head];
                    if (idn == idm) sv -= 100.0f;   // faithful to source: -100 where EQUAL
                    vals[ni] = sv;
                    rowmax = fmaxf(rowmax, sv);
                }
#pragma unroll
                for (int msk = 8; msk >= 1; msk >>= 1)
                    rowmax = fmaxf(rowmax, __shfl_xor(rowmax, msk, 64));
                float rsum = 0.f;
#pragma unroll
                for (int ni = 0; ni < 4; ni++) {
                    const float p = __expf(vals[ni] - rowmax);
                    vals[ni] = p;
                    rsum += p;
                }
#pragma unroll
                for (int msk = 8; msk >= 1; msk >>= 1)
                    rsum += __shfl_xor(rsum, msk, 64);
                const float inv = 1.0f / rsum;
#pragma unroll
                for (int ni = 0; ni < 4; ni++)
                    P_lds[w][n * 64 + ni * 16 + lr] = (bf16)(vals[ni] * inv);
            }

        // PV: O[n][d] = sum_key P[n][key] V[key][d]  (operand-swapped: lane holds
        // 4 consecutive d of one row)
        f32x4 o[4][2];
#pragma unroll
        for (int i = 0; i < 4; i++)
#pragma unroll
            for (int j = 0; j < 2; j++) o[i][j] = z4;
#pragma unroll
        for (int kk = 0; kk < 2; kk++) {
            bf16x8 bv[2];
#pragma unroll
            for (int ni = 0; ni < 2; ni++)
#pragma unroll
                for (int i = 0; i < 8; i++)
                    bv[ni][i] = vp[(kk * 32 + lk + i) * 768 + ni * 16 + lr];
#pragma unroll
            for (int mi = 0; mi < 4; mi++) {
                const bf16x8 ap = *(const bf16x8*)&P_lds[w][(mi * 16 + lr) * 64 + kk * 32 + lk];
#pragma unroll
                for (int ni = 0; ni < 2; ni++)
                    o[mi][ni] = __builtin_amdgcn_mfma_f32_16x16x32_bf16(bv[ni], ap, o[mi][ni], 0, 0, 0);
            }
        }
        // store: lane holds o[mi][ni][0..3] = out[row n=mi*16+lr][d=ni*16+lg*4 ..+3]
#pragma unroll
        for (int mi = 0; mi < 4; mi++)
#pragma unroll
            for (int ni = 0; ni < 2; ni++) {
                const int n = mi * 16 + lr;
                const int d = ni * 16 + lg * 4;
                bf16x4 ov;
                ov[0] = (bf16)o[mi][ni][0]; ov[1] = (bf16)o[mi][ni][1];
                ov[2] = (bf16)o[mi][ni][2]; ov[3] = (bf16)o[mi][ni][3];
                *(bf16x4*)(out + ((long)(win * 64 + n)) * 256 + head * 32 + d) = ov;
            }
    }
}

extern "C" void kernel_launch(void* const* d_in, const int* in_sizes, int n_in,
                              void* d_out, int out_size, void* d_ws, size_t ws_size,
                              hipStream_t stream)
{
    (void)in_sizes; (void)n_in; (void)out_size;
    const float* x      = (const float*)d_in[0];
    const float* n1g    = (const float*)d_in[1];
    const float* n1b    = (const float*)d_in[2];
    const float* qkv_w  = (const float*)d_in[3];
    const float* qkv_b  = (const float*)d_in[4];
    const float* rpb    = (const float*)d_in[5];
    const float* proj_w = (const float*)d_in[6];
    const float* proj_b = (const float*)d_in[7];
    const float* n2g    = (const float*)d_in[8];
    const float* n2b    = (const float*)d_in[9];
    const float* fc1_w  = (const float*)d_in[10];
    const float* fc1_b  = (const float*)d_in[11];
    const float* fc2_w  = (const float*)d_in[12];
    const float* fc2_b  = (const float*)d_in[13];
    float* out = (float*)d_out;

    // workspace plan (total 136,314,880 B = 130 MB):
    //   0        .. 2 MB   : transposed bf16 weights
    //   2 MB     .. 34 MB  : xw  -> later attn_o -> later part of hbuf
    //   34 MB    .. 130 MB : qkvb -> later proj_o (first 32MB) -> part of hbuf
    //   xn2 staged in d_out (first 32 MB as bf16; dead before FC2 writes)
    char* ws = (char*)d_ws;
    bf16* qkv_wt  = (bf16*)(ws + 0);          // 768x256
    bf16* proj_wt = (bf16*)(ws + 393216);     // 256x256
    bf16* fc1_wt  = (bf16*)(ws + 524288);     // 1024x256
    bf16* fc2_wt  = (bf16*)(ws + 1048576);    // 256x1024
    bf16* xw      = (bf16*)(ws + 2097152);    // 32MB  [65536][256]
    bf16* qkvb    = (bf16*)(ws + 35651584);   // 96MB  [65536][768]
    bf16* attn_o  = xw;                       // reuse xw (dead after QKV gemm)
    bf16* proj_o  = qkvb;                     // reuse qkvb (dead after attn), 32MB
    bf16* xn2     = (bf16*)d_out;             // stage LN2 output in d_out
    bf16* hbuf    = xw;                       // 128MB over 2..130MB
    if (ws_size < 136314880ull) return;       // insufficient scratch

    const size_t LB = 73728;   // 72 KB dynamic LDS (3-stage 256x128 tile)

    wprep_all<<<3072, 256, 0, stream>>>(qkv_w, proj_w, fc1_w, fc2_w,
                                        qkv_wt, proj_wt, fc1_wt, fc2_wt);

    ln1_window<<<16384, 256, 0, stream>>>(x, n1g, n1b, xw);
    gemm_w<0><<<1536, 512, LB, stream>>>(xw, qkv_wt, qkv_b, qkvb, 768, 256, nullptr, 6, 1536);
    attn_kernel<<<1024, 256, 0, stream>>>(qkvb, rpb, attn_o);
    gemm_w<1><<<512, 512, LB, stream>>>(attn_o, proj_wt, proj_b, proj_o, 256, 256, nullptr, 2, 512);
    ln2_kernel<<<16384, 256, 0, stream>>>(x, proj_o, n2g, n2b, xn2);
    gemm_w<2><<<2048, 512, LB, stream>>>(xn2, fc1_wt, fc1_b, hbuf, 1024, 256, nullptr, 8, 2048);
    gemm_w<3><<<512, 512, LB, stream>>>(hbuf, fc2_wt, fc2_b, out, 256, 1024, x, 2, 512);
}

// Round 8
// 290.383 us; speedup vs baseline: 1.2330x; 1.1058x over previous
//
#include <hip/hip_runtime.h>
#include <math.h>

typedef __bf16 bf16;
typedef __bf16 bf16x4 __attribute__((ext_vector_type(4)));
typedef __bf16 bf16x8 __attribute__((ext_vector_type(8)));
typedef float f32x4 __attribute__((ext_vector_type(4)));

#define AS1 __attribute__((address_space(1)))
#define AS3 __attribute__((address_space(3)))

__device__ __forceinline__ void gload_lds16(const bf16* g, bf16* l) {
    __builtin_amdgcn_global_load_lds((const AS1 void*)g, (AS3 void*)l, 16, 0, 0);
}

__device__ __forceinline__ float gelu_fast(float v) {
    const float u = 1.5957691216057308f * (v + 0.044715f * v * v * v);
    return v / (1.0f + __expf(-u));
}

// ---------------- all weight transposes + cast in ONE launch
__global__ __launch_bounds__(256)
void wprep_all(const float* __restrict__ qkv_w, const float* __restrict__ proj_w,
               const float* __restrict__ fc1_w, const float* __restrict__ fc2_w,
               bf16* __restrict__ qkv_wt, bf16* __restrict__ proj_wt,
               bf16* __restrict__ fc1_wt, bf16* __restrict__ fc2_wt)
{
    int idx = blockIdx.x * 256 + threadIdx.x;
    const float* src; bf16* dst; int K, N;
    if (idx < 196608)            { src = qkv_w;  dst = qkv_wt;  K = 256;  N = 768; }
    else if (idx < 262144)       { idx -= 196608; src = proj_w; dst = proj_wt; K = 256;  N = 256; }
    else if (idx < 524288)       { idx -= 262144; src = fc1_w;  dst = fc1_wt;  K = 256;  N = 1024; }
    else                         { idx -= 524288; src = fc2_w;  dst = fc2_wt;  K = 1024; N = 256; }
    const int k = idx / N, n = idx % N;
    dst[(long)n * K + k] = (bf16)src[idx];
}

// ---------------- LN1 + cyclic shift(-4,-4) + window partition -> xw bf16 [B*64win][64][256]
__global__ __launch_bounds__(256)
void ln1_window(const float* __restrict__ x, const float* __restrict__ g,
                const float* __restrict__ be, bf16* __restrict__ xw)
{
    const int t = threadIdx.x;
    const int lane = t & 63;
    const int w = t >> 6;
    const long tok = (long)blockIdx.x * 4 + w;
    const float4 v = ((const float4*)(x + tok * 256))[lane];
    float sum = v.x + v.y + v.z + v.w;
    float sq  = v.x * v.x + v.y * v.y + v.z * v.z + v.w * v.w;
#pragma unroll
    for (int m = 32; m >= 1; m >>= 1) {
        sum += __shfl_xor(sum, m, 64);
        sq  += __shfl_xor(sq,  m, 64);
    }
    const float mean = sum * (1.0f / 256.0f);
    const float var  = sq * (1.0f / 256.0f) - mean * mean;
    const float rstd = rsqrtf(var + 1e-5f);
    const float4 gv = ((const float4*)g)[lane];
    const float4 bv = ((const float4*)be)[lane];
    bf16x4 ov;
    ov[0] = (bf16)((v.x - mean) * rstd * gv.x + bv.x);
    ov[1] = (bf16)((v.y - mean) * rstd * gv.y + bv.y);
    ov[2] = (bf16)((v.z - mean) * rstd * gv.z + bv.z);
    ov[3] = (bf16)((v.w - mean) * rstd * gv.w + bv.w);
    const int b = (int)(tok >> 12);
    const int l = (int)(tok & 4095);
    const int i = l >> 6, j = l & 63;
    const int ip = (i + 60) & 63, jp = (j + 60) & 63;   // shifted coords
    const int winl = ((ip >> 3) << 3) + (jp >> 3);
    const int n = ((ip & 7) << 3) + (jp & 7);
    const long drow = ((long)b * 64 + winl) * 64 + n;
    *(bf16x4*)(xw + drow * 256 + lane * 4) = ov;
}

// ---------------- LN2: y = x + proj_out, then layernorm -> xn2 bf16
__global__ __launch_bounds__(256)
void ln2_kernel(const float* __restrict__ x, const bf16* __restrict__ pj,
                const float* __restrict__ g, const float* __restrict__ be,
                bf16* __restrict__ xn2)
{
    const int t = threadIdx.x;
    const int lane = t & 63;
    const int w = t >> 6;
    const long tok = (long)blockIdx.x * 4 + w;
    const float4 xv = ((const float4*)(x + tok * 256))[lane];
    const bf16x4 pv = *(const bf16x4*)(pj + tok * 256 + lane * 4);
    float y0 = xv.x + (float)pv[0];
    float y1 = xv.y + (float)pv[1];
    float y2 = xv.z + (float)pv[2];
    float y3 = xv.w + (float)pv[3];
    float sum = y0 + y1 + y2 + y3;
    float sq  = y0 * y0 + y1 * y1 + y2 * y2 + y3 * y3;
#pragma unroll
    for (int m = 32; m >= 1; m >>= 1) {
        sum += __shfl_xor(sum, m, 64);
        sq  += __shfl_xor(sq,  m, 64);
    }
    const float mean = sum * (1.0f / 256.0f);
    const float var  = sq * (1.0f / 256.0f) - mean * mean;
    const float rstd = rsqrtf(var + 1e-5f);
    const float4 gv = ((const float4*)g)[lane];
    const float4 bv = ((const float4*)be)[lane];
    bf16x4 ov;
    ov[0] = (bf16)((y0 - mean) * rstd * gv.x + bv.x);
    ov[1] = (bf16)((y1 - mean) * rstd * gv.y + bv.y);
    ov[2] = (bf16)((y2 - mean) * rstd * gv.z + bv.z);
    ov[3] = (bf16)((y3 - mean) * rstd * gv.w + bv.w);
    *(bf16x4*)(xn2 + tok * 256 + lane * 4) = ov;
}

// ---------------- GEMM 256x128 tile, 8 waves, BK=32, 3-stage counted pipeline,
// XOR-swizzled LDS (0 conflicts), XCD remap, operand-swapped vectorized epilogue.
// EPI 0: +bias -> bf16 qkvb; V-columns (col>=512) additionally TRANSPOSED into
//        vT[win][d][key] (aux) instead of qkvb               (QKV)
// EPI 1: +bias -> bf16 out[unwindowed tok*256]  (proj, window-reverse + roll(+4))
// EPI 2: +bias, fast GELU -> bf16 out           (FC1)
// EPI 3: +bias + x residual -> f32 out          (FC2)
template<int EPI>
__global__ __launch_bounds__(512, 2)
void gemm_w(const bf16* __restrict__ A, const bf16* __restrict__ Bt,
            const float* __restrict__ bias, void* __restrict__ outp,
            int N, int K, const float* __restrict__ xres, void* __restrict__ aux,
            int gx, int nb)
{
    extern __shared__ bf16 lds[];
    bf16* sA = lds;                 // 3 bufs x 8192 elems (256x32)
    bf16* sB = lds + 3 * 8192;      // 3 bufs x 4096 elems (128x32)
    const int t = threadIdx.x;      // 0..511
    const int l = t & 63;
    const int w = t >> 6;           // 0..7
    const int wr = w >> 1, wc = w & 1;
    const int q = nb >> 3;
    const int id = ((int)blockIdx.x & 7) * q + ((int)blockIdx.x >> 3);
    const long m0 = (long)(id / gx) * 256;
    const long n0 = (long)(id % gx) * 128;

    long asrc[2]; int adst[2];
#pragma unroll
    for (int j = 0; j < 2; j++) {
        const int idx = j * 512 + t;
        const int p = idx >> 3, s = idx & 7;
        const int sl = s ^ (p & 7);
        const int row = 2 * p + (sl >> 2);
        const int ce = (sl & 3) * 8;
        asrc[j] = (m0 + row) * (long)K + ce;
        adst[j] = idx * 8;
    }
    long bsrc; int bdst;
    {
        const int idx = t;
        const int p = idx >> 3, s = idx & 7;
        const int sl = s ^ (p & 7);
        const int row = 2 * p + (sl >> 2);
        const int ce = (sl & 3) * 8;
        bsrc = (n0 + row) * (long)K + ce;
        bdst = idx * 8;
    }

    f32x4 acc[4][4];
#pragma unroll
    for (int i = 0; i < 4; i++)
#pragma unroll
        for (int j = 0; j < 4; j++) acc[i][j] = (f32x4){0.f, 0.f, 0.f, 0.f};

    const int KT = K >> 5;
    const int c = l >> 4;
    const int ra = wr * 64 + (l & 15);
    const int rb = wc * 64 + (l & 15);

#define STAGE(bufi, ko)                                                        \
    do {                                                                       \
        gload_lds16(A + asrc[0] + (ko), &sA[(bufi) * 8192 + adst[0]]);         \
        gload_lds16(A + asrc[1] + (ko), &sA[(bufi) * 8192 + adst[1]]);         \
        gload_lds16(Bt + bsrc + (ko), &sB[(bufi) * 4096 + bdst]);              \
    } while (0)

#define COMPUTE(bufi)                                                          \
    do {                                                                       \
        bf16x8 av[4], bv[4];                                                   \
        _Pragma("unroll")                                                      \
        for (int ni = 0; ni < 4; ni++) {                                       \
            const int row = rb + ni * 16;                                      \
            const int p = row >> 1;                                            \
            const int s = (((row & 1) << 2) + c) ^ (p & 7);                    \
            bv[ni] = *(const bf16x8*)&sB[(bufi) * 4096 + (p * 8 + s) * 8];     \
        }                                                                      \
        _Pragma("unroll")                                                      \
        for (int mi = 0; mi < 4; mi++) {                                       \
            const int row = ra + mi * 16;                                      \
            const int p = row >> 1;                                            \
            const int s = (((row & 1) << 2) + c) ^ (p & 7);                    \
            av[mi] = *(const bf16x8*)&sA[(bufi) * 8192 + (p * 8 + s) * 8];     \
        }                                                                      \
        _Pragma("unroll")                                                      \
        for (int mi = 0; mi < 4; mi++)                                         \
            _Pragma("unroll")                                                  \
            for (int ni = 0; ni < 4; ni++)                                     \
                acc[mi][ni] = __builtin_amdgcn_mfma_f32_16x16x32_bf16(         \
                    bv[ni], av[mi], acc[mi][ni], 0, 0, 0);                     \
    } while (0)

    STAGE(0, 0);
    STAGE(1, 32);

    int buf = 0;
    for (int kt = 0; kt < KT - 1; ++kt) {
        asm volatile("s_waitcnt vmcnt(3)" ::: "memory");
        __builtin_amdgcn_s_barrier();
        __builtin_amdgcn_sched_barrier(0);
        if (kt + 2 < KT) {
            const int nbuf = (buf + 2 >= 3) ? buf - 1 : buf + 2;
            STAGE(nbuf, (long)(kt + 2) * 32);
        }
        COMPUTE(buf);
        buf = (buf + 1 == 3) ? 0 : buf + 1;
    }
    asm volatile("s_waitcnt vmcnt(0)" ::: "memory");
    __builtin_amdgcn_s_barrier();
    __builtin_amdgcn_sched_barrier(0);
    COMPUTE(buf);
#undef STAGE
#undef COMPUTE

#pragma unroll
    for (int mi = 0; mi < 4; mi++)
#pragma unroll
        for (int ni = 0; ni < 4; ni++) {
            const long row = m0 + wr * 64 + mi * 16 + (l & 15);
            const int col = (int)(n0 + wc * 64 + ni * 16 + (l >> 4) * 4);
            const float4 bz = *(const float4*)&bias[col];
            float vv[4];
            vv[0] = acc[mi][ni][0] + bz.x;
            vv[1] = acc[mi][ni][1] + bz.y;
            vv[2] = acc[mi][ni][2] + bz.z;
            vv[3] = acc[mi][ni][3] + bz.w;
            if constexpr (EPI == 2) {
#pragma unroll
                for (int j = 0; j < 4; j++) vv[j] = gelu_fast(vv[j]);
            }
            if constexpr (EPI == 3) {
                const float4 xr = *(const float4*)&xres[row * N + col];
                float4 ov = {vv[0] + xr.x, vv[1] + xr.y, vv[2] + xr.z, vv[3] + xr.w};
                *(float4*)&((float*)outp)[row * N + col] = ov;
            } else if constexpr (EPI == 0) {
                if (col >= 512) {
                    // V columns -> vT[win][d][key] (transposed scalar stores)
                    bf16* vt = (bf16*)aux;
                    const int win = (int)(row >> 6);
                    const int n = (int)(row & 63);
#pragma unroll
                    for (int j = 0; j < 4; j++)
                        vt[(long)win * 16384 + (col - 512 + j) * 64 + n] = (bf16)vv[j];
                } else {
                    bf16x4 ov;
#pragma unroll
                    for (int j = 0; j < 4; j++) ov[j] = (bf16)vv[j];
                    *(bf16x4*)&((bf16*)outp)[row * N + col] = ov;
                }
            } else {
                bf16x4 ov;
#pragma unroll
                for (int j = 0; j < 4; j++) ov[j] = (bf16)vv[j];
                if constexpr (EPI == 1) {
                    const int gwin = (int)(row >> 6);
                    const int n = (int)(row & 63);
                    const int bb = gwin >> 6, wi = gwin & 63;
                    const int ipp = ((wi >> 3) << 3) + (n >> 3);
                    const int jpp = ((wi & 7) << 3) + (n & 7);
                    const int ii = (ipp + 4) & 63, jj = (jpp + 4) & 63;
                    const long tok = ((long)bb << 12) + (ii << 6) + jj;
                    *(bf16x4*)&((bf16*)outp)[tok * 256 + col] = ov;
                } else {
                    *(bf16x4*)&((bf16*)outp)[row * N + col] = ov;
                }
            }
        }
    (void)xres; (void)aux;
}

// ---------------- per-window attention: 2048 blocks, 4 waves, ONE head per wave.
// win = bid>>1, head = (bid&1)*4 + wave. V read vectorized from vT[win][d][key].
// P_lds XOR-swizzled (colE ^= (row&7)<<3) -> no 16-way read conflicts.
__global__ __launch_bounds__(256, 4)
void attn_kernel(const bf16* __restrict__ qkv, const bf16* __restrict__ vT,
                 const float* __restrict__ rpb, bf16* __restrict__ out)
{
    __shared__ bf16 P_lds[4][64 * 64];
    const int t = threadIdx.x;
    const int lane = t & 63;
    const int w = t >> 6;
    const int win = blockIdx.x >> 1;
    const int head = (blockIdx.x & 1) * 4 + w;
    const int wi = win & 63;
    const int lr = lane & 15;
    const int lg = lane >> 4;
    const int lk = lg * 8;
    const long base = (long)win * 64 * 768;
    const float scale = 0.17677669529663687f;   // 32^-0.5
    const int whb = (wi >> 3) << 3;
    const int wwb = (wi & 7) << 3;
    const f32x4 z4 = {0.f, 0.f, 0.f, 0.f};

    const bf16* qp  = qkv + base + head * 32;
    const bf16* kp  = qkv + base + 256 + head * 32;
    const bf16* vtp = vT + (long)win * 16384 + head * 32 * 64;

    // hoisted: region id of key m = ni*16+lr (per lane)
    int idm[4];
#pragma unroll
    for (int ni = 0; ni < 4; ni++) {
        const int m = ni * 16 + lr;
        const int gi2 = whb + (m >> 3), gj2 = wwb + (m & 7);
        idm[ni] = (gi2 < 56 ? 0 : (gi2 < 60 ? 1 : 2)) * 3 + (gj2 < 56 ? 0 : (gj2 < 60 ? 1 : 2));
    }

    bf16x8 aq[4], bk[4];
#pragma unroll
    for (int mi = 0; mi < 4; mi++)
        aq[mi] = *(const bf16x8*)(qp + (mi * 16 + lr) * 768 + lk);
#pragma unroll
    for (int ni = 0; ni < 4; ni++)
        bk[ni] = *(const bf16x8*)(kp + (ni * 16 + lr) * 768 + lk);

    f32x4 s[4][4];
#pragma unroll
    for (int i = 0; i < 4; i++)
#pragma unroll
        for (int j = 0; j < 4; j++) s[i][j] = z4;
#pragma unroll
    for (int mi = 0; mi < 4; mi++)
#pragma unroll
        for (int ni = 0; ni < 4; ni++)
            s[mi][ni] = __builtin_amdgcn_mfma_f32_16x16x32_bf16(aq[mi], bk[ni], s[mi][ni], 0, 0, 0);

    // bias + mask + softmax; row n held by 16 lanes sharing lg (4 col-tiles each)
#pragma unroll
    for (int mi = 0; mi < 4; mi++)
#pragma unroll
        for (int r = 0; r < 4; r++) {
            const int n = mi * 16 + lg * 4 + r;
            const int gi = whb + (n >> 3);
            const int gj = wwb + (n & 7);
            const int idn = (gi < 56 ? 0 : (gi < 60 ? 1 : 2)) * 3 + (gj < 56 ? 0 : (gj < 60 ? 1 : 2));
            float vals[4];
            float rowmax = -3.0e38f;
#pragma unroll
            for (int ni = 0; ni < 4; ni++) {
                const int m = ni * 16 + lr;
                const int dj = (n & 7) - (m & 7);
                const int di = (n >> 3) - (m >> 3);
                float sv = s[mi][ni][r] * scale + rpb[((dj + 7) * 15 + (di + 7)) * 8 + head];
                if (idn == idm[ni]) sv -= 100.0f;   // faithful: -100 where EQUAL
                vals[ni] = sv;
                rowmax = fmaxf(rowmax, sv);
            }
#pragma unroll
            for (int msk = 8; msk >= 1; msk >>= 1)
                rowmax = fmaxf(rowmax, __shfl_xor(rowmax, msk, 64));
            float rsum = 0.f;
#pragma unroll
            for (int ni = 0; ni < 4; ni++) {
                const float p = __expf(vals[ni] - rowmax);
                vals[ni] = p;
                rsum += p;
            }
#pragma unroll
            for (int msk = 8; msk >= 1; msk >>= 1)
                rsum += __shfl_xor(rsum, msk, 64);
            const float inv = 1.0f / rsum;
            const int swz = (n & 7) << 3;
#pragma unroll
            for (int ni = 0; ni < 4; ni++)
                P_lds[w][n * 64 + ((ni * 16 + lr) ^ swz)] = (bf16)(vals[ni] * inv);
        }

    // PV (operand-swapped): o = mfma(bv, ap); bv = V^T fragment (vector load)
    f32x4 o[4][2];
#pragma unroll
    for (int i = 0; i < 4; i++)
#pragma unroll
        for (int j = 0; j < 2; j++) o[i][j] = z4;
#pragma unroll
    for (int kk = 0; kk < 2; kk++) {
        bf16x8 bv[2];
#pragma unroll
        for (int ni = 0; ni < 2; ni++)
            bv[ni] = *(const bf16x8*)&vtp[(ni * 16 + lr) * 64 + kk * 32 + lk];
#pragma unroll
        for (int mi = 0; mi < 4; mi++) {
            const int row = mi * 16 + lr;
            const bf16x8 ap = *(const bf16x8*)&P_lds[w][row * 64 + ((kk * 32 + lk) ^ ((row & 7) << 3))];
#pragma unroll
            for (int ni = 0; ni < 2; ni++)
                o[mi][ni] = __builtin_amdgcn_mfma_f32_16x16x32_bf16(bv[ni], ap, o[mi][ni], 0, 0, 0);
        }
    }
    // store: lane holds o[mi][ni][0..3] = out[n=mi*16+lr][d=ni*16+lg*4 ..+3]
#pragma unroll
    for (int mi = 0; mi < 4; mi++)
#pragma unroll
        for (int ni = 0; ni < 2; ni++) {
            const int n = mi * 16 + lr;
            const int d = ni * 16 + lg * 4;
            bf16x4 ov;
            ov[0] = (bf16)o[mi][ni][0]; ov[1] = (bf16)o[mi][ni][1];
            ov[2] = (bf16)o[mi][ni][2]; ov[3] = (bf16)o[mi][ni][3];
            *(bf16x4*)(out + ((long)(win * 64 + n)) * 256 + head * 32 + d) = ov;
        }
}

extern "C" void kernel_launch(void* const* d_in, const int* in_sizes, int n_in,
                              void* d_out, int out_size, void* d_ws, size_t ws_size,
                              hipStream_t stream)
{
    (void)in_sizes; (void)n_in; (void)out_size;
    const float* x      = (const float*)d_in[0];
    const float* n1g    = (const float*)d_in[1];
    const float* n1b    = (const float*)d_in[2];
    const float* qkv_w  = (const float*)d_in[3];
    const float* qkv_b  = (const float*)d_in[4];
    const float* rpb    = (const float*)d_in[5];
    const float* proj_w = (const float*)d_in[6];
    const float* proj_b = (const float*)d_in[7];
    const float* n2g    = (const float*)d_in[8];
    const float* n2b    = (const float*)d_in[9];
    const float* fc1_w  = (const float*)d_in[10];
    const float* fc1_b  = (const float*)d_in[11];
    const float* fc2_w  = (const float*)d_in[12];
    const float* fc2_b  = (const float*)d_in[13];
    float* out = (float*)d_out;

    // workspace plan (130 MB):
    //   0..2MB weights | 2..34MB xw->attn_o->hbuf | 34..130MB qkvb->proj_o->hbuf
    //   vT (32MB, V^T per window) staged in d_out during QKV+attn (dead after)
    //   xn2 staged in d_out after proj (dead before FC2 writes d_out)
    char* ws = (char*)d_ws;
    bf16* qkv_wt  = (bf16*)(ws + 0);          // 768x256
    bf16* proj_wt = (bf16*)(ws + 393216);     // 256x256
    bf16* fc1_wt  = (bf16*)(ws + 524288);     // 1024x256
    bf16* fc2_wt  = (bf16*)(ws + 1048576);    // 256x1024
    bf16* xw      = (bf16*)(ws + 2097152);    // 32MB  [65536][256]
    bf16* qkvb    = (bf16*)(ws + 35651584);   // 96MB  [65536][768] (V cols unused)
    bf16* attn_o  = xw;                       // reuse xw (dead after QKV gemm)
    bf16* proj_o  = qkvb;                     // reuse qkvb (dead after attn)
    bf16* vT      = (bf16*)d_out;             // V^T staging in d_out
    bf16* xn2     = (bf16*)d_out;             // LN2 out staging in d_out
    bf16* hbuf    = xw;                       // 128MB over 2..130MB
    if (ws_size < 136314880ull) return;       // insufficient scratch

    const size_t LB = 73728;   // 72 KB dynamic LDS (3-stage 256x128 tile)

    wprep_all<<<3072, 256, 0, stream>>>(qkv_w, proj_w, fc1_w, fc2_w,
                                        qkv_wt, proj_wt, fc1_wt, fc2_wt);

    ln1_window<<<16384, 256, 0, stream>>>(x, n1g, n1b, xw);
    gemm_w<0><<<1536, 512, LB, stream>>>(xw, qkv_wt, qkv_b, qkvb, 768, 256, nullptr, vT, 6, 1536);
    attn_kernel<<<2048, 256, 0, stream>>>(qkvb, vT, rpb, attn_o);
    gemm_w<1><<<512, 512, LB, stream>>>(attn_o, proj_wt, proj_b, proj_o, 256, 256, nullptr, nullptr, 2, 512);
    ln2_kernel<<<16384, 256, 0, stream>>>(x, proj_o, n2g, n2b, xn2);
    gemm_w<2><<<2048, 512, LB, stream>>>(xn2, fc1_wt, fc1_b, hbuf, 1024, 256, nullptr, nullptr, 8, 2048);
    gemm_w<3><<<512, 512, LB, stream>>>(hbuf, fc2_wt, fc2_b, out, 256, 1024, x, nullptr, 2, 512);
}

// Round 9
// 281.803 us; speedup vs baseline: 1.2706x; 1.0304x over previous
//
#include <hip/hip_runtime.h>
#include <math.h>

typedef __bf16 bf16;
typedef __bf16 bf16x4 __attribute__((ext_vector_type(4)));
typedef __bf16 bf16x8 __attribute__((ext_vector_type(8)));
typedef float f32x4 __attribute__((ext_vector_type(4)));

#define AS1 __attribute__((address_space(1)))
#define AS3 __attribute__((address_space(3)))

__device__ __forceinline__ void gload_lds16(const bf16* g, bf16* l) {
    __builtin_amdgcn_global_load_lds((const AS1 void*)g, (AS3 void*)l, 16, 0, 0);
}

__device__ __forceinline__ float gelu_fast(float v) {
    const float u = 1.5957691216057308f * (v + 0.044715f * v * v * v);
    return v / (1.0f + __expf(-u));
}

// ---------------- all weight transposes + cast in ONE launch
__global__ __launch_bounds__(256)
void wprep_all(const float* __restrict__ qkv_w, const float* __restrict__ proj_w,
               const float* __restrict__ fc1_w, const float* __restrict__ fc2_w,
               bf16* __restrict__ qkv_wt, bf16* __restrict__ proj_wt,
               bf16* __restrict__ fc1_wt, bf16* __restrict__ fc2_wt)
{
    int idx = blockIdx.x * 256 + threadIdx.x;
    const float* src; bf16* dst; int K, N;
    if (idx < 196608)            { src = qkv_w;  dst = qkv_wt;  K = 256;  N = 768; }
    else if (idx < 262144)       { idx -= 196608; src = proj_w; dst = proj_wt; K = 256;  N = 256; }
    else if (idx < 524288)       { idx -= 262144; src = fc1_w;  dst = fc1_wt;  K = 256;  N = 1024; }
    else                         { idx -= 524288; src = fc2_w;  dst = fc2_wt;  K = 1024; N = 256; }
    const int k = idx / N, n = idx % N;
    dst[(long)n * K + k] = (bf16)src[idx];
}

// ---------------- LN1 + cyclic shift(-4,-4) + window partition -> xw bf16 [B*64win][64][256]
__global__ __launch_bounds__(256)
void ln1_window(const float* __restrict__ x, const float* __restrict__ g,
                const float* __restrict__ be, bf16* __restrict__ xw)
{
    const int t = threadIdx.x;
    const int lane = t & 63;
    const int w = t >> 6;
    const long tok = (long)blockIdx.x * 4 + w;
    const float4 v = ((const float4*)(x + tok * 256))[lane];
    float sum = v.x + v.y + v.z + v.w;
    float sq  = v.x * v.x + v.y * v.y + v.z * v.z + v.w * v.w;
#pragma unroll
    for (int m = 32; m >= 1; m >>= 1) {
        sum += __shfl_xor(sum, m, 64);
        sq  += __shfl_xor(sq,  m, 64);
    }
    const float mean = sum * (1.0f / 256.0f);
    const float var  = sq * (1.0f / 256.0f) - mean * mean;
    const float rstd = rsqrtf(var + 1e-5f);
    const float4 gv = ((const float4*)g)[lane];
    const float4 bv = ((const float4*)be)[lane];
    bf16x4 ov;
    ov[0] = (bf16)((v.x - mean) * rstd * gv.x + bv.x);
    ov[1] = (bf16)((v.y - mean) * rstd * gv.y + bv.y);
    ov[2] = (bf16)((v.z - mean) * rstd * gv.z + bv.z);
    ov[3] = (bf16)((v.w - mean) * rstd * gv.w + bv.w);
    const int b = (int)(tok >> 12);
    const int l = (int)(tok & 4095);
    const int i = l >> 6, j = l & 63;
    const int ip = (i + 60) & 63, jp = (j + 60) & 63;   // shifted coords
    const int winl = ((ip >> 3) << 3) + (jp >> 3);
    const int n = ((ip & 7) << 3) + (jp & 7);
    const long drow = ((long)b * 64 + winl) * 64 + n;
    *(bf16x4*)(xw + drow * 256 + lane * 4) = ov;
}

// ---------------- LN2: y = x + proj_out, then layernorm -> xn2 bf16
__global__ __launch_bounds__(256)
void ln2_kernel(const float* __restrict__ x, const bf16* __restrict__ pj,
                const float* __restrict__ g, const float* __restrict__ be,
                bf16* __restrict__ xn2)
{
    const int t = threadIdx.x;
    const int lane = t & 63;
    const int w = t >> 6;
    const long tok = (long)blockIdx.x * 4 + w;
    const float4 xv = ((const float4*)(x + tok * 256))[lane];
    const bf16x4 pv = *(const bf16x4*)(pj + tok * 256 + lane * 4);
    float y0 = xv.x + (float)pv[0];
    float y1 = xv.y + (float)pv[1];
    float y2 = xv.z + (float)pv[2];
    float y3 = xv.w + (float)pv[3];
    float sum = y0 + y1 + y2 + y3;
    float sq  = y0 * y0 + y1 * y1 + y2 * y2 + y3 * y3;
#pragma unroll
    for (int m = 32; m >= 1; m >>= 1) {
        sum += __shfl_xor(sum, m, 64);
        sq  += __shfl_xor(sq,  m, 64);
    }
    const float mean = sum * (1.0f / 256.0f);
    const float var  = sq * (1.0f / 256.0f) - mean * mean;
    const float rstd = rsqrtf(var + 1e-5f);
    const float4 gv = ((const float4*)g)[lane];
    const float4 bv = ((const float4*)be)[lane];
    bf16x4 ov;
    ov[0] = (bf16)((y0 - mean) * rstd * gv.x + bv.x);
    ov[1] = (bf16)((y1 - mean) * rstd * gv.y + bv.y);
    ov[2] = (bf16)((y2 - mean) * rstd * gv.z + bv.z);
    ov[3] = (bf16)((y3 - mean) * rstd * gv.w + bv.w);
    *(bf16x4*)(xn2 + tok * 256 + lane * 4) = ov;
}

// ---------------- GEMM 256x128 tile, 8 waves, BK=32, 3-stage counted pipeline,
// K-loop FULLY UNROLLED (KT compile-time): buf indices and LDS/global offsets
// fold to immediates; per-thread swizzled addresses computed once pre-loop.
// XOR-swizzled LDS (0 conflicts), XCD remap, operand-swapped vectorized epilogue.
template<int EPI, int KT>
__global__ __launch_bounds__(512, 2)
void gemm_w(const bf16* __restrict__ A, const bf16* __restrict__ Bt,
            const float* __restrict__ bias, void* __restrict__ outp,
            int N, const float* __restrict__ xres, void* __restrict__ aux,
            int gx, int nb)
{
    constexpr int K = KT * 32;
    extern __shared__ bf16 lds[];
    bf16* sA = lds;                 // 3 bufs x 8192 elems (256x32)
    bf16* sB = lds + 3 * 8192;      // 3 bufs x 4096 elems (128x32)
    const int t = threadIdx.x;      // 0..511
    const int l = t & 63;
    const int w = t >> 6;           // 0..7
    const int wr = w >> 1, wc = w & 1;
    const int q = nb >> 3;
    const int id = ((int)blockIdx.x & 7) * q + ((int)blockIdx.x >> 3);
    const long m0 = (long)(id / gx) * 256;
    const long n0 = (long)(id % gx) * 128;

    // staging sources (element offsets), swizzle baked into global src
    const bf16* asrcp[2]; bf16* adstp[2];
#pragma unroll
    for (int j = 0; j < 2; j++) {
        const int idx = j * 512 + t;
        const int p = idx >> 3, s = idx & 7;
        const int sl = s ^ (p & 7);
        const int row = 2 * p + (sl >> 2);
        const int ce = (sl & 3) * 8;
        asrcp[j] = A + (m0 + row) * (long)K + ce;
        adstp[j] = &sA[idx * 8];
    }
    const bf16* bsrcp; bf16* bdstp;
    {
        const int p = t >> 3, s = t & 7;
        const int sl = s ^ (p & 7);
        const int row = 2 * p + (sl >> 2);
        const int ce = (sl & 3) * 8;
        bsrcp = Bt + (n0 + row) * (long)K + ce;
        bdstp = &sB[t * 8];
    }

    // per-thread LDS read element-offsets (loop-invariant)
    const int c = l >> 4;
    int eA[4], eB[4];
#pragma unroll
    for (int i = 0; i < 4; i++) {
        const int rowA = wr * 64 + (l & 15) + i * 16;
        const int pa = rowA >> 1;
        eA[i] = (pa * 8 + ((((rowA & 1) << 2) + c) ^ (pa & 7))) * 8;
        const int rowB = wc * 64 + (l & 15) + i * 16;
        const int pb = rowB >> 1;
        eB[i] = (pb * 8 + ((((rowB & 1) << 2) + c) ^ (pb & 7))) * 8;
    }

    f32x4 acc[4][4];
#pragma unroll
    for (int i = 0; i < 4; i++)
#pragma unroll
        for (int j = 0; j < 4; j++) acc[i][j] = (f32x4){0.f, 0.f, 0.f, 0.f};

#define STAGE(bufi, ko)                                                        \
    do {                                                                       \
        gload_lds16(asrcp[0] + (ko), adstp[0] + (bufi) * 8192);                \
        gload_lds16(asrcp[1] + (ko), adstp[1] + (bufi) * 8192);                \
        gload_lds16(bsrcp + (ko), bdstp + (bufi) * 4096);                      \
    } while (0)

    // prologue: stage tiles 0 and 1 (6 loads outstanding)
    STAGE(0, 0);
    STAGE(1, 32);

#pragma unroll
    for (int kt = 0; kt < KT; ++kt) {
        const int buf = kt % 3;                 // compile-time after unroll
        if (kt < KT - 1)
            asm volatile("s_waitcnt vmcnt(3)" ::: "memory");
        else
            asm volatile("s_waitcnt vmcnt(0)" ::: "memory");
        __builtin_amdgcn_s_barrier();
        __builtin_amdgcn_sched_barrier(0);
        if (kt + 2 < KT)
            STAGE((kt + 2) % 3, (kt + 2) * 32);
        bf16x8 av[4], bv[4];
#pragma unroll
        for (int ni = 0; ni < 4; ni++)
            bv[ni] = *(const bf16x8*)&sB[buf * 4096 + eB[ni]];
#pragma unroll
        for (int mi = 0; mi < 4; mi++)
            av[mi] = *(const bf16x8*)&sA[buf * 8192 + eA[mi]];
#pragma unroll
        for (int mi = 0; mi < 4; mi++)
#pragma unroll
            for (int ni = 0; ni < 4; ni++)
                acc[mi][ni] = __builtin_amdgcn_mfma_f32_16x16x32_bf16(
                    bv[ni], av[mi], acc[mi][ni], 0, 0, 0);
    }
#undef STAGE

    // epilogue: lane holds out[row][col..col+3] per (mi,ni)
#pragma unroll
    for (int mi = 0; mi < 4; mi++)
#pragma unroll
        for (int ni = 0; ni < 4; ni++) {
            const long row = m0 + wr * 64 + mi * 16 + (l & 15);
            const int col = (int)(n0 + wc * 64 + ni * 16 + (l >> 4) * 4);
            const float4 bz = *(const float4*)&bias[col];
            float vv[4];
            vv[0] = acc[mi][ni][0] + bz.x;
            vv[1] = acc[mi][ni][1] + bz.y;
            vv[2] = acc[mi][ni][2] + bz.z;
            vv[3] = acc[mi][ni][3] + bz.w;
            if constexpr (EPI == 2) {
#pragma unroll
                for (int j = 0; j < 4; j++) vv[j] = gelu_fast(vv[j]);
            }
            if constexpr (EPI == 3) {
                const float4 xr = *(const float4*)&xres[row * N + col];
                float4 ov = {vv[0] + xr.x, vv[1] + xr.y, vv[2] + xr.z, vv[3] + xr.w};
                *(float4*)&((float*)outp)[row * N + col] = ov;
            } else if constexpr (EPI == 0) {
                if (col >= 512) {
                    bf16* vt = (bf16*)aux;
                    const int win = (int)(row >> 6);
                    const int n = (int)(row & 63);
#pragma unroll
                    for (int j = 0; j < 4; j++)
                        vt[(long)win * 16384 + (col - 512 + j) * 64 + n] = (bf16)vv[j];
                } else {
                    bf16x4 ov;
#pragma unroll
                    for (int j = 0; j < 4; j++) ov[j] = (bf16)vv[j];
                    *(bf16x4*)&((bf16*)outp)[row * N + col] = ov;
                }
            } else {
                bf16x4 ov;
#pragma unroll
                for (int j = 0; j < 4; j++) ov[j] = (bf16)vv[j];
                if constexpr (EPI == 1) {
                    const int gwin = (int)(row >> 6);
                    const int n = (int)(row & 63);
                    const int bb = gwin >> 6, wi = gwin & 63;
                    const int ipp = ((wi >> 3) << 3) + (n >> 3);
                    const int jpp = ((wi & 7) << 3) + (n & 7);
                    const int ii = (ipp + 4) & 63, jj = (jpp + 4) & 63;
                    const long tok = ((long)bb << 12) + (ii << 6) + jj;
                    *(bf16x4*)&((bf16*)outp)[tok * 256 + col] = ov;
                } else {
                    *(bf16x4*)&((bf16*)outp)[row * N + col] = ov;
                }
            }
        }
    (void)xres; (void)aux;
}

// ---------------- per-window attention: 2048 blocks, 4 waves, ONE head per wave.
// win = bid>>1, head = (bid&1)*4 + wave. V read vectorized from vT[win][d][key].
// P_lds XOR-swizzled (colE ^= (row&7)<<3) -> no 16-way read conflicts.
__global__ __launch_bounds__(256, 4)
void attn_kernel(const bf16* __restrict__ qkv, const bf16* __restrict__ vT,
                 const float* __restrict__ rpb, bf16* __restrict__ out)
{
    __shared__ bf16 P_lds[4][64 * 64];
    const int t = threadIdx.x;
    const int lane = t & 63;
    const int w = t >> 6;
    const int win = blockIdx.x >> 1;
    const int head = (blockIdx.x & 1) * 4 + w;
    const int wi = win & 63;
    const int lr = lane & 15;
    const int lg = lane >> 4;
    const int lk = lg * 8;
    const long base = (long)win * 64 * 768;
    const float scale = 0.17677669529663687f;   // 32^-0.5
    const int whb = (wi >> 3) << 3;
    const int wwb = (wi & 7) << 3;
    const f32x4 z4 = {0.f, 0.f, 0.f, 0.f};

    const bf16* qp  = qkv + base + head * 32;
    const bf16* kp  = qkv + base + 256 + head * 32;
    const bf16* vtp = vT + (long)win * 16384 + head * 32 * 64;

    int idm[4];
#pragma unroll
    for (int ni = 0; ni < 4; ni++) {
        const int m = ni * 16 + lr;
        const int gi2 = whb + (m >> 3), gj2 = wwb + (m & 7);
        idm[ni] = (gi2 < 56 ? 0 : (gi2 < 60 ? 1 : 2)) * 3 + (gj2 < 56 ? 0 : (gj2 < 60 ? 1 : 2));
    }

    bf16x8 aq[4], bk[4];
#pragma unroll
    for (int mi = 0; mi < 4; mi++)
        aq[mi] = *(const bf16x8*)(qp + (mi * 16 + lr) * 768 + lk);
#pragma unroll
    for (int ni = 0; ni < 4; ni++)
        bk[ni] = *(const bf16x8*)(kp + (ni * 16 + lr) * 768 + lk);

    f32x4 s[4][4];
#pragma unroll
    for (int i = 0; i < 4; i++)
#pragma unroll
        for (int j = 0; j < 4; j++) s[i][j] = z4;
#pragma unroll
    for (int mi = 0; mi < 4; mi++)
#pragma unroll
        for (int ni = 0; ni < 4; ni++)
            s[mi][ni] = __builtin_amdgcn_mfma_f32_16x16x32_bf16(aq[mi], bk[ni], s[mi][ni], 0, 0, 0);

#pragma unroll
    for (int mi = 0; mi < 4; mi++)
#pragma unroll
        for (int r = 0; r < 4; r++) {
            const int n = mi * 16 + lg * 4 + r;
            const int gi = whb + (n >> 3);
            const int gj = wwb + (n & 7);
            const int idn = (gi < 56 ? 0 : (gi < 60 ? 1 : 2)) * 3 + (gj < 56 ? 0 : (gj < 60 ? 1 : 2));
            float vals[4];
            float rowmax = -3.0e38f;
#pragma unroll
            for (int ni = 0; ni < 4; ni++) {
                const int m = ni * 16 + lr;
                const int dj = (n & 7) - (m & 7);
                const int di = (n >> 3) - (m >> 3);
                float sv = s[mi][ni][r] * scale + rpb[((dj + 7) * 15 + (di + 7)) * 8 + head];
                if (idn == idm[ni]) sv -= 100.0f;   // faithful: -100 where EQUAL
                vals[ni] = sv;
                rowmax = fmaxf(rowmax, sv);
            }
#pragma unroll
            for (int msk = 8; msk >= 1; msk >>= 1)
                rowmax = fmaxf(rowmax, __shfl_xor(rowmax, msk, 64));
            float rsum = 0.f;
#pragma unroll
            for (int ni = 0; ni < 4; ni++) {
                const float p = __expf(vals[ni] - rowmax);
                vals[ni] = p;
                rsum += p;
            }
#pragma unroll
            for (int msk = 8; msk >= 1; msk >>= 1)
                rsum += __shfl_xor(rsum, msk, 64);
            const float inv = 1.0f / rsum;
            const int swz = (n & 7) << 3;
#pragma unroll
            for (int ni = 0; ni < 4; ni++)
                P_lds[w][n * 64 + ((ni * 16 + lr) ^ swz)] = (bf16)(vals[ni] * inv);
        }

    f32x4 o[4][2];
#pragma unroll
    for (int i = 0; i < 4; i++)
#pragma unroll
        for (int j = 0; j < 2; j++) o[i][j] = z4;
#pragma unroll
    for (int kk = 0; kk < 2; kk++) {
        bf16x8 bv[2];
#pragma unroll
        for (int ni = 0; ni < 2; ni++)
            bv[ni] = *(const bf16x8*)&vtp[(ni * 16 + lr) * 64 + kk * 32 + lk];
#pragma unroll
        for (int mi = 0; mi < 4; mi++) {
            const int row = mi * 16 + lr;
            const bf16x8 ap = *(const bf16x8*)&P_lds[w][row * 64 + ((kk * 32 + lk) ^ ((row & 7) << 3))];
#pragma unroll
            for (int ni = 0; ni < 2; ni++)
                o[mi][ni] = __builtin_amdgcn_mfma_f32_16x16x32_bf16(bv[ni], ap, o[mi][ni], 0, 0, 0);
        }
    }
#pragma unroll
    for (int mi = 0; mi < 4; mi++)
#pragma unroll
        for (int ni = 0; ni < 2; ni++) {
            const int n = mi * 16 + lr;
            const int d = ni * 16 + lg * 4;
            bf16x4 ov;
            ov[0] = (bf16)o[mi][ni][0]; ov[1] = (bf16)o[mi][ni][1];
            ov[2] = (bf16)o[mi][ni][2]; ov[3] = (bf16)o[mi][ni][3];
            *(bf16x4*)(out + ((long)(win * 64 + n)) * 256 + head * 32 + d) = ov;
        }
}

extern "C" void kernel_launch(void* const* d_in, const int* in_sizes, int n_in,
                              void* d_out, int out_size, void* d_ws, size_t ws_size,
                              hipStream_t stream)
{
    (void)in_sizes; (void)n_in; (void)out_size;
    const float* x      = (const float*)d_in[0];
    const float* n1g    = (const float*)d_in[1];
    const float* n1b    = (const float*)d_in[2];
    const float* qkv_w  = (const float*)d_in[3];
    const float* qkv_b  = (const float*)d_in[4];
    const float* rpb    = (const float*)d_in[5];
    const float* proj_w = (const float*)d_in[6];
    const float* proj_b = (const float*)d_in[7];
    const float* n2g    = (const float*)d_in[8];
    const float* n2b    = (const float*)d_in[9];
    const float* fc1_w  = (const float*)d_in[10];
    const float* fc1_b  = (const float*)d_in[11];
    const float* fc2_w  = (const float*)d_in[12];
    const float* fc2_b  = (const float*)d_in[13];
    float* out = (float*)d_out;

    // workspace plan (130 MB):
    //   0..2MB weights | 2..34MB xw->attn_o->hbuf | 34..130MB qkvb->proj_o->hbuf
    //   vT (32MB) + xn2 staged in d_out (both dead before FC2 writes d_out)
    char* ws = (char*)d_ws;
    bf16* qkv_wt  = (bf16*)(ws + 0);          // 768x256
    bf16* proj_wt = (bf16*)(ws + 393216);     // 256x256
    bf16* fc1_wt  = (bf16*)(ws + 524288);     // 1024x256
    bf16* fc2_wt  = (bf16*)(ws + 1048576);    // 256x1024
    bf16* xw      = (bf16*)(ws + 2097152);    // 32MB  [65536][256]
    bf16* qkvb    = (bf16*)(ws + 35651584);   // 96MB  [65536][768] (V cols unused)
    bf16* attn_o  = xw;                       // reuse xw (dead after QKV gemm)
    bf16* proj_o  = qkvb;                     // reuse qkvb (dead after attn)
    bf16* vT      = (bf16*)d_out;             // V^T staging in d_out
    bf16* xn2     = (bf16*)d_out;             // LN2 out staging in d_out
    bf16* hbuf    = xw;                       // 128MB over 2..130MB
    if (ws_size < 136314880ull) return;       // insufficient scratch

    const size_t LB = 73728;   // 72 KB dynamic LDS (3-stage 256x128 tile)

    wprep_all<<<3072, 256, 0, stream>>>(qkv_w, proj_w, fc1_w, fc2_w,
                                        qkv_wt, proj_wt, fc1_wt, fc2_wt);

    ln1_window<<<16384, 256, 0, stream>>>(x, n1g, n1b, xw);
    gemm_w<0, 8><<<1536, 512, LB, stream>>>(xw, qkv_wt, qkv_b, qkvb, 768, nullptr, vT, 6, 1536);
    attn_kernel<<<2048, 256, 0, stream>>>(qkvb, vT, rpb, attn_o);
    gemm_w<1, 8><<<512, 512, LB, stream>>>(attn_o, proj_wt, proj_b, proj_o, 256, nullptr, nullptr, 2, 512);
    ln2_kernel<<<16384, 256, 0, stream>>>(x, proj_o, n2g, n2b, xn2);
    gemm_w<2, 8><<<2048, 512, LB, stream>>>(xn2, fc1_wt, fc1_b, hbuf, 1024, nullptr, nullptr, 8, 2048);
    gemm_w<3, 32><<<512, 512, LB, stream>>>(hbuf, fc2_wt, fc2_b, out, 256, x, nullptr, 2, 512);
}